// Round 1
// baseline (9431.347 us; speedup 1.0000x reference)
//
#include <hip/hip_runtime.h>
#include <math.h>

#define BATCH   1024
#define SEQ     80
#define EMB     512
#define UNITS   512
#define ROWS    4      // batch rows per block
#define THREADS 256    // 4 waves; each thread owns 2 columns

__global__ __launch_bounds__(THREADS) void rnn_fused_kernel(
    const int*   __restrict__ inputs,  // [BATCH, SEQ] int32
    const float* __restrict__ emb,     // [VOCAB, EMB]
    const float* __restrict__ W0x,     // [EMB, UNITS]
    const float* __restrict__ W0h,     // [UNITS, UNITS]
    const float* __restrict__ b0,      // [UNITS]
    const float* __restrict__ W1x,     // [UNITS, UNITS]
    const float* __restrict__ W1h,     // [UNITS, UNITS]
    const float* __restrict__ b1,      // [UNITS]
    const float* __restrict__ Wout,    // [UNITS, 1]
    const float* __restrict__ bout,    // [1]
    float*       __restrict__ out)     // [BATCH, 1]
{
    __shared__ float xb[ROWS][EMB];
    __shared__ float h0[ROWS][UNITS];
    __shared__ float h1[ROWS][UNITS];

    const int tid   = threadIdx.x;
    const int bbase = blockIdx.x * ROWS;
    const int c0    = tid;          // first owned column
    const int c1    = tid + 256;    // second owned column

    // zero-init hidden state
    for (int i = tid; i < ROWS * UNITS; i += THREADS) {
        (&h0[0][0])[i] = 0.f;
        (&h1[0][0])[i] = 0.f;
    }
    __syncthreads();

    const float bias0_c0 = b0[c0], bias0_c1 = b0[c1];
    const float bias1_c0 = b1[c0], bias1_c1 = b1[c1];

    for (int t = 0; t < SEQ; ++t) {
        // ---- stage x_t rows (embedding gather) into LDS ----
        for (int i = tid; i < ROWS * (EMB / 4); i += THREADS) {
            int r  = i / (EMB / 4);
            int c4 = i % (EMB / 4);
            int idx = inputs[(bbase + r) * SEQ + t];
            ((float4*)xb[r])[c4] = ((const float4*)(emb + (size_t)idx * EMB))[c4];
        }
        __syncthreads();

        // ---- layer 0: pre = x @ W0x + h0 @ W0h + b0 ----
        float acc[ROWS][2];
#pragma unroll
        for (int r = 0; r < ROWS; ++r) { acc[r][0] = bias0_c0; acc[r][1] = bias0_c1; }

        for (int k = 0; k < EMB; k += 4) {
            float4 xk[ROWS], hk[ROWS];
#pragma unroll
            for (int r = 0; r < ROWS; ++r) {
                xk[r] = *(const float4*)&xb[r][k];
                hk[r] = *(const float4*)&h0[r][k];
            }
#pragma unroll
            for (int kk = 0; kk < 4; ++kk) {
                const float* wxrow = W0x + (size_t)(k + kk) * UNITS;
                const float* whrow = W0h + (size_t)(k + kk) * UNITS;
                float wx0 = wxrow[c0], wx1 = wxrow[c1];
                float wh0 = whrow[c0], wh1 = whrow[c1];
#pragma unroll
                for (int r = 0; r < ROWS; ++r) {
                    float xv = ((const float*)&xk[r])[kk];
                    float hv = ((const float*)&hk[r])[kk];
                    acc[r][0] += xv * wx0 + hv * wh0;
                    acc[r][1] += xv * wx1 + hv * wh1;
                }
            }
        }
        __syncthreads();   // everyone done reading old h0
#pragma unroll
        for (int r = 0; r < ROWS; ++r) {
            h0[r][c0] = tanhf(acc[r][0]);
            h0[r][c1] = tanhf(acc[r][1]);
        }
        __syncthreads();   // new h0 visible

        // ---- layer 1: pre = h0_new @ W1x + h1 @ W1h + b1 ----
        float acc1[ROWS][2];
#pragma unroll
        for (int r = 0; r < ROWS; ++r) { acc1[r][0] = bias1_c0; acc1[r][1] = bias1_c1; }

        for (int k = 0; k < UNITS; k += 4) {
            float4 gk[ROWS], hk[ROWS];
#pragma unroll
            for (int r = 0; r < ROWS; ++r) {
                gk[r] = *(const float4*)&h0[r][k];
                hk[r] = *(const float4*)&h1[r][k];
            }
#pragma unroll
            for (int kk = 0; kk < 4; ++kk) {
                const float* wxrow = W1x + (size_t)(k + kk) * UNITS;
                const float* whrow = W1h + (size_t)(k + kk) * UNITS;
                float wx0 = wxrow[c0], wx1 = wxrow[c1];
                float wh0 = whrow[c0], wh1 = whrow[c1];
#pragma unroll
                for (int r = 0; r < ROWS; ++r) {
                    float gv = ((const float*)&gk[r])[kk];
                    float hv = ((const float*)&hk[r])[kk];
                    acc1[r][0] += gv * wx0 + hv * wh0;
                    acc1[r][1] += gv * wx1 + hv * wh1;
                }
            }
        }
        __syncthreads();   // everyone done reading old h1
#pragma unroll
        for (int r = 0; r < ROWS; ++r) {
            h1[r][c0] = tanhf(acc1[r][0]);
            h1[r][c1] = tanhf(acc1[r][1]);
        }
        __syncthreads();   // new h1 visible
    }

    // ---- output: sigmoid(h1 @ Wout + bout), one wave per row ----
    const int w    = tid >> 6;
    const int lane = tid & 63;
    if (w < ROWS) {
        float s = 0.f;
#pragma unroll
        for (int j = 0; j < UNITS / 64; ++j) {
            int c = lane + j * 64;
            s += h1[w][c] * Wout[c];
        }
#pragma unroll
        for (int off = 32; off > 0; off >>= 1) s += __shfl_down(s, off);
        if (lane == 0) {
            float z = s + bout[0];
            out[bbase + w] = 1.f / (1.f + expf(-z));
        }
    }
}

extern "C" void kernel_launch(void* const* d_in, const int* in_sizes, int n_in,
                              void* d_out, int out_size, void* d_ws, size_t ws_size,
                              hipStream_t stream) {
    const int*   inputs = (const int*)d_in[0];
    const float* emb    = (const float*)d_in[1];
    const float* W0x    = (const float*)d_in[2];
    const float* W0h    = (const float*)d_in[3];
    const float* b0     = (const float*)d_in[4];
    const float* W1x    = (const float*)d_in[5];
    const float* W1h    = (const float*)d_in[6];
    const float* b1     = (const float*)d_in[7];
    const float* Wout   = (const float*)d_in[8];
    const float* bout   = (const float*)d_in[9];
    float*       out    = (float*)d_out;

    dim3 grid(BATCH / ROWS);   // 256 blocks
    dim3 block(THREADS);
    rnn_fused_kernel<<<grid, block, 0, stream>>>(
        inputs, emb, W0x, W0h, b0, W1x, W1h, b1, Wout, bout, out);
}

// Round 2
// 5666.673 us; speedup vs baseline: 1.6644x; 1.6644x over previous
//
#include <hip/hip_runtime.h>
#include <hip/hip_bf16.h>
#include <math.h>

#define BATCH   1024
#define SEQ     80
#define EMB     512
#define UNITS   512
#define ROWS    16
#define NBLK    (BATCH / ROWS)   // 64 persistent blocks
#define THREADS 512              // 8 waves; each wave owns 64 output cols
#define LDW     1544             // LDS row stride in bf16: 1536 (x|h0|h1) + 8 pad (breaks bank conflicts)

typedef __attribute__((ext_vector_type(8))) short          bf16x8;
typedef __attribute__((ext_vector_type(8))) unsigned short u16x8;
typedef __attribute__((ext_vector_type(4))) float          f32x4;

__device__ inline unsigned short f2bf(float f) {
    __hip_bfloat16 h = __float2bfloat16(f);
    return *reinterpret_cast<unsigned short*>(&h);
}
__device__ inline float bf2f(unsigned short u) {
    unsigned int x = ((unsigned int)u) << 16;
    return __uint_as_float(x);
}
__device__ inline float tanh_fast(float x) {
    float e = __expf(2.f * x);
    return 1.f - 2.f / (e + 1.f);   // exact at +-inf saturation
}

// ---------------------------------------------------------------------------
// Pack weights (fp32 row-major [K][N]) into MFMA B-fragment order, bf16.
// Phase 0: K=1024 rows = [W0x; W0h].  Phase 1: K=1024 rows = [W1x; W1h].
// elem index = p*524288 + ((NT*32 + k0)*64 + lane)*8 + j
//   value    = W[k0*32 + (lane>>4)*8 + j][NT*16 + (lane&15)]
// One wave per (p, NT, k0) triple: 2*32*32 = 2048 waves = 512 blocks x 256 thr.
// ---------------------------------------------------------------------------
__global__ __launch_bounds__(256) void pack_weights(
    const float* __restrict__ W0x, const float* __restrict__ W0h,
    const float* __restrict__ W1x, const float* __restrict__ W1h,
    unsigned short* __restrict__ wpack)
{
    int g    = blockIdx.x * 4 + (threadIdx.x >> 6);  // wave id 0..2047
    int lane = threadIdx.x & 63;
    int p    = g >> 10;
    int NT   = (g >> 5) & 31;
    int k0   = g & 31;
    int n    = NT * 16 + (lane & 15);
    int kb   = k0 * 32 + (lane >> 4) * 8;
    const float* Wx = p ? W1x : W0x;
    const float* Wh = p ? W1h : W0h;

    u16x8 v;
#pragma unroll
    for (int j = 0; j < 8; ++j) {
        int k = kb + j;
        float f = (k < 512) ? Wx[(size_t)k * UNITS + n]
                            : Wh[(size_t)(k - 512) * UNITS + n];
        v[j] = f2bf(f);
    }
    size_t idx = (size_t)p * 524288 + ((size_t)(NT * 32 + k0) * 64 + lane) * 8;
    *(u16x8*)(wpack + idx) = v;
}

// ---------------------------------------------------------------------------
// Persistent recurrent kernel: 64 blocks x 16 batch rows, 80 steps, no grid sync.
// LDS rows: [ x (512) | h0 (512) | h1 (512) | pad 8 ] bf16.
// Phase1: pre0 = [x|h0] @ [W0x;W0h] + b0  (A = cols 0..1023)
// Phase2: pre1 = [h0'|h1] @ [W1x;W1h] + b1 (A = cols 512..1535)
// ---------------------------------------------------------------------------
__global__ __launch_bounds__(THREADS, 2) void rnn_mfma_kernel(
    const int*   __restrict__ inputs,
    const float* __restrict__ emb,
    const float* __restrict__ b0,
    const float* __restrict__ b1,
    const unsigned short* __restrict__ wpack,
    const float* __restrict__ Wout,
    const float* __restrict__ bout,
    float*       __restrict__ out)
{
    __shared__ unsigned short hcat[ROWS * LDW];

    const int tid   = threadIdx.x;
    const int w     = tid >> 6;        // wave 0..7 -> cols [w*64, w*64+64)
    const int lane  = tid & 63;
    const int quad  = lane >> 4;
    const int l15   = lane & 15;
    const int bbase = blockIdx.x * ROWS;

    // zero h0,h1 regions (cols 512..1535)
    for (int i = tid; i < ROWS * 1024; i += THREADS) {
        int r = i >> 10, c = i & 1023;
        hcat[r * LDW + 512 + c] = 0;
    }

    // x staging map: 32 threads per row, 16 floats each
    const int xr = tid >> 5;
    const int xc = (tid & 31) * 16;

    // stage x_0
    {
        int idx = inputs[(bbase + xr) * SEQ + 0];
        const float4* ep = (const float4*)(emb + (size_t)idx * EMB + xc);
        float4 p0 = ep[0], p1 = ep[1], p2 = ep[2], p3 = ep[3];
        u16x8 v0, v1;
        v0[0]=f2bf(p0.x); v0[1]=f2bf(p0.y); v0[2]=f2bf(p0.z); v0[3]=f2bf(p0.w);
        v0[4]=f2bf(p1.x); v0[5]=f2bf(p1.y); v0[6]=f2bf(p1.z); v0[7]=f2bf(p1.w);
        v1[0]=f2bf(p2.x); v1[1]=f2bf(p2.y); v1[2]=f2bf(p2.z); v1[3]=f2bf(p2.w);
        v1[4]=f2bf(p3.x); v1[5]=f2bf(p3.y); v1[6]=f2bf(p3.z); v1[7]=f2bf(p3.w);
        *(u16x8*)(hcat + xr * LDW + xc)     = v0;
        *(u16x8*)(hcat + xr * LDW + xc + 8) = v1;
    }
    __syncthreads();

    // bias per owned column tile
    float bias0[4], bias1[4];
#pragma unroll
    for (int nt = 0; nt < 4; ++nt) {
        int col = w * 64 + nt * 16 + l15;
        bias0[nt] = b0[col];
        bias1[nt] = b1[col];
    }

    // per-lane packed-weight base pointers (nt adds nt*16384, k0 adds k0*512)
    const unsigned short* wp0 = wpack + (size_t)w * 65536 + (size_t)lane * 8;
    const unsigned short* wp1 = wp0 + 524288;

    // A-fragment LDS base (elem offset); add kbase + k0*32
    const int abase = l15 * LDW + quad * 8;

    // depth-2 pipelined MFMA phase over K=1024 (32 k0 steps)
#define RUN_PHASE(ACC, KBASE, WP)                                              \
    do {                                                                       \
        const unsigned short* a_lds = hcat + abase + (KBASE);                  \
        bf16x8 Afr[3]; bf16x8 Bfr[3][4];                                       \
        Afr[0] = *(const bf16x8*)(a_lds);                                      \
        Afr[1] = *(const bf16x8*)(a_lds + 32);                                 \
        _Pragma("unroll")                                                      \
        for (int nt = 0; nt < 4; ++nt) {                                       \
            Bfr[0][nt] = *(const bf16x8*)((WP) + nt * 16384);                  \
            Bfr[1][nt] = *(const bf16x8*)((WP) + nt * 16384 + 512);            \
        }                                                                      \
        _Pragma("unroll")                                                      \
        for (int k0 = 0; k0 < 32; ++k0) {                                      \
            if (k0 + 2 < 32) {                                                 \
                int sl = (k0 + 2) % 3;                                         \
                Afr[sl] = *(const bf16x8*)(a_lds + (k0 + 2) * 32);             \
                _Pragma("unroll")                                              \
                for (int nt = 0; nt < 4; ++nt)                                 \
                    Bfr[sl][nt] = *(const bf16x8*)((WP) + nt * 16384 +         \
                                                   (k0 + 2) * 512);            \
            }                                                                  \
            int cu = k0 % 3;                                                   \
            _Pragma("unroll")                                                  \
            for (int nt = 0; nt < 4; ++nt)                                     \
                ACC[nt] = __builtin_amdgcn_mfma_f32_16x16x32_bf16(             \
                    Afr[cu], Bfr[cu][nt], ACC[nt], 0, 0, 0);                   \
        }                                                                      \
    } while (0)

    for (int t = 0; t < SEQ; ++t) {
        // register-prefetch x_{t+1} (hidden under phase1 compute)
        int tn = (t < SEQ - 1) ? (t + 1) : t;
        int idx = inputs[(bbase + xr) * SEQ + tn];
        const float4* ep = (const float4*)(emb + (size_t)idx * EMB + xc);
        float4 p0 = ep[0], p1 = ep[1], p2 = ep[2], p3 = ep[3];

        // ---- phase 1: pre0 = [x|h0] @ Wp0 + b0 ----
        f32x4 acc[4];
#pragma unroll
        for (int nt = 0; nt < 4; ++nt)
            acc[nt] = (f32x4){bias0[nt], bias0[nt], bias0[nt], bias0[nt]};
        RUN_PHASE(acc, 0, wp0);
        __syncthreads();   // all reads of x,h0 done

        // write h0' (cols 512..1023)
#pragma unroll
        for (int nt = 0; nt < 4; ++nt) {
            int col = 512 + w * 64 + nt * 16 + l15;
#pragma unroll
            for (int i = 0; i < 4; ++i)
                hcat[(quad * 4 + i) * LDW + col] = f2bf(tanh_fast(acc[nt][i]));
        }
        // write x_{t+1} (cols 0..511)
        {
            u16x8 v0, v1;
            v0[0]=f2bf(p0.x); v0[1]=f2bf(p0.y); v0[2]=f2bf(p0.z); v0[3]=f2bf(p0.w);
            v0[4]=f2bf(p1.x); v0[5]=f2bf(p1.y); v0[6]=f2bf(p1.z); v0[7]=f2bf(p1.w);
            v1[0]=f2bf(p2.x); v1[1]=f2bf(p2.y); v1[2]=f2bf(p2.z); v1[3]=f2bf(p2.w);
            v1[4]=f2bf(p3.x); v1[5]=f2bf(p3.y); v1[6]=f2bf(p3.z); v1[7]=f2bf(p3.w);
            *(u16x8*)(hcat + xr * LDW + xc)     = v0;
            *(u16x8*)(hcat + xr * LDW + xc + 8) = v1;
        }
        __syncthreads();   // h0', x_{t+1} visible

        // ---- phase 2: pre1 = [h0'|h1] @ Wp1 + b1 ----
        f32x4 acc2[4];
#pragma unroll
        for (int nt = 0; nt < 4; ++nt)
            acc2[nt] = (f32x4){bias1[nt], bias1[nt], bias1[nt], bias1[nt]};
        RUN_PHASE(acc2, 512, wp1);
        __syncthreads();   // all reads of h1 done

        // write h1' (cols 1024..1535)
#pragma unroll
        for (int nt = 0; nt < 4; ++nt) {
            int col = 1024 + w * 64 + nt * 16 + l15;
#pragma unroll
            for (int i = 0; i < 4; ++i)
                hcat[(quad * 4 + i) * LDW + col] = f2bf(tanh_fast(acc2[nt][i]));
        }
        // no barrier needed: next phase1 reads cols 0..1023 only; h1' ordered
        // ahead of next phase2 by the next two barriers.
    }
    __syncthreads();

    // ---- epilogue: out = sigmoid(h1 @ Wout + bout), 2 rows per wave ----
#pragma unroll
    for (int rr = 0; rr < 2; ++rr) {
        int r = w * 2 + rr;
        float s = 0.f;
#pragma unroll
        for (int j = 0; j < 8; ++j) {
            int c = lane + 64 * j;
            s += bf2f(hcat[r * LDW + 1024 + c]) * Wout[c];
        }
#pragma unroll
        for (int off = 32; off > 0; off >>= 1) s += __shfl_down(s, off);
        if (lane == 0) {
            float z = s + bout[0];
            out[bbase + r] = 1.f / (1.f + __expf(-z));
        }
    }
#undef RUN_PHASE
}

extern "C" void kernel_launch(void* const* d_in, const int* in_sizes, int n_in,
                              void* d_out, int out_size, void* d_ws, size_t ws_size,
                              hipStream_t stream) {
    const int*   inputs = (const int*)d_in[0];
    const float* emb    = (const float*)d_in[1];
    const float* W0x    = (const float*)d_in[2];
    const float* W0h    = (const float*)d_in[3];
    const float* b0     = (const float*)d_in[4];
    const float* W1x    = (const float*)d_in[5];
    const float* W1h    = (const float*)d_in[6];
    const float* b1     = (const float*)d_in[7];
    const float* Wout   = (const float*)d_in[8];
    const float* bout   = (const float*)d_in[9];
    float*       out    = (float*)d_out;

    unsigned short* wpack = (unsigned short*)d_ws;  // 2 MB packed bf16 weights

    pack_weights<<<512, 256, 0, stream>>>(W0x, W0h, W1x, W1h, wpack);
    rnn_mfma_kernel<<<NBLK, THREADS, 0, stream>>>(
        inputs, emb, b0, b1, wpack, Wout, bout, out);
}

// Round 3
// 1136.683 us; speedup vs baseline: 8.2973x; 4.9853x over previous
//
#include <hip/hip_runtime.h>
#include <hip/hip_bf16.h>
#include <math.h>

#define BATCH   1024
#define SEQ     80
#define EMB     512
#define UNITS   512
#define NBG     64           // batch groups (16 rows each)
#define NCG     4            // col groups (128 cols each); siblings = blockIdx +-64 -> same XCD
#define ROWS    16
#define COLS    128
#define THREADS 512          // 8 waves; wave w owns col tile [cg*128 + w*16, +16)
#define LDW     1544         // LDS row stride (ushort): 1536 + 8 pad

#define H0_OFF   (2u * 1024 * 1024)
#define H1_OFF   (4u * 1024 * 1024)
#define FLAG_OFF (6u * 1024 * 1024)

typedef __attribute__((ext_vector_type(8))) short          bf16x8;
typedef __attribute__((ext_vector_type(8))) unsigned short u16x8;
typedef __attribute__((ext_vector_type(4))) float          f32x4;

__device__ inline unsigned short f2bf(float f) {
    __hip_bfloat16 h = __float2bfloat16(f);
    return *reinterpret_cast<unsigned short*>(&h);
}
__device__ inline float bf2f(unsigned short u) {
    unsigned int x = ((unsigned int)u) << 16;
    return __uint_as_float(x);
}
__device__ inline float tanh_fast(float x) {
    float e = __expf(2.f * x);
    return 1.f - 2.f / (e + 1.f);
}

// ---------------------------------------------------------------------------
// Pack weights into per-(phase, cg, wave) contiguous B-fragment slabs, bf16.
// slab id g = ((p*NCG + cg)*8 + w)*32 + k0 ; elem = g*512 + lane*8 + j
// value = Wp[k0*32 + (lane>>4)*8 + j][cg*128 + w*16 + (lane&15)]
// Wp rows: [Wx ; Wh] stacked (K=1024).
// ---------------------------------------------------------------------------
__global__ __launch_bounds__(256) void pack_weights(
    const float* __restrict__ W0x, const float* __restrict__ W0h,
    const float* __restrict__ W1x, const float* __restrict__ W1h,
    unsigned short* __restrict__ wpack)
{
    int g    = blockIdx.x * 4 + (threadIdx.x >> 6);   // 0..2047
    int lane = threadIdx.x & 63;
    int p    = g >> 10;
    int cg   = (g >> 8) & 3;
    int w    = (g >> 5) & 7;
    int k0   = g & 31;
    int n    = cg * COLS + w * 16 + (lane & 15);
    int kb   = k0 * 32 + (lane >> 4) * 8;
    const float* Wx = p ? W1x : W0x;
    const float* Wh = p ? W1h : W0h;

    u16x8 v;
#pragma unroll
    for (int j = 0; j < 8; ++j) {
        int k = kb + j;
        float f = (k < 512) ? Wx[(size_t)k * UNITS + n]
                            : Wh[(size_t)(k - 512) * UNITS + n];
        v[j] = f2bf(f);
    }
    *(u16x8*)(wpack + (size_t)g * 512 + lane * 8) = v;
}

// depth-8 static prefetch; k0&7 constant-folds under full unroll (no spills)
#define RUN_PHASE(ACC, KBASE, WB)                                              \
    do {                                                                       \
        const unsigned short* a_lds = hcat + abase + (KBASE);                  \
        bf16x8 Bf[8];                                                          \
        _Pragma("unroll")                                                      \
        for (int i = 0; i < 8; ++i)                                            \
            Bf[i] = *(const bf16x8*)((WB) + (size_t)i * 512);                  \
        _Pragma("unroll")                                                      \
        for (int k0 = 0; k0 < 32; ++k0) {                                      \
            bf16x8 a = *(const bf16x8*)(a_lds + k0 * 32);                      \
            bf16x8 b = Bf[k0 & 7];                                             \
            if (k0 + 8 < 32)                                                   \
                Bf[k0 & 7] = *(const bf16x8*)((WB) + (size_t)(k0 + 8) * 512);  \
            ACC = __builtin_amdgcn_mfma_f32_16x16x32_bf16(a, b, ACC, 0, 0, 0); \
        }                                                                      \
    } while (0)

// ---------------------------------------------------------------------------
// 256 blocks = 64 bg x 4 cg, all co-resident (1/CU). Per block: 16 rows,
// 128 cols. LDS A rows: [ x | h0 | h1 ] bf16. Per step: phase1 -> publish
// h0' slice (agent-scope) -> flag/spin -> gather full h0' -> phase2 ->
// publish h1' -> flag/spin -> gather full h1'.
// ---------------------------------------------------------------------------
__global__ __launch_bounds__(THREADS, 1) void rnn_ex_kernel(
    const int*   __restrict__ inputs,
    const float* __restrict__ emb,
    const float* __restrict__ b0,
    const float* __restrict__ b1,
    const unsigned short* __restrict__ wpack,
    unsigned short* __restrict__ h0buf,   // [2][1024][512] bf16
    unsigned short* __restrict__ h1buf,   // [2][1024][512] bf16
    int* __restrict__ flag0,              // [64][4]
    int* __restrict__ flag1,              // [64][4]
    const float* __restrict__ Wout,
    const float* __restrict__ bout,
    float*       __restrict__ out)
{
    __shared__ unsigned short hcat[ROWS * LDW];

    const int tid   = threadIdx.x;
    const int w     = tid >> 6;
    const int lane  = tid & 63;
    const int quad  = lane >> 4;
    const int l15   = lane & 15;
    const int cg    = blockIdx.x >> 6;    // 0..3
    const int bg    = blockIdx.x & 63;    // 0..63
    const int rbase = bg * ROWS;

    // zero h0,h1 (cols 512..1535)
    for (int i = tid; i < ROWS * 1024; i += THREADS) {
        int r = i >> 10, c = i & 1023;
        hcat[r * LDW + 512 + c] = 0;
    }

    const int xr = tid >> 5;          // staging: row 0..15
    const int xc = (tid & 31) * 16;   // 16 cols per thread

    // stage x_0
    {
        int idx = inputs[(rbase + xr) * SEQ + 0];
        const float4* ep = (const float4*)(emb + (size_t)idx * EMB + xc);
        float4 p0 = ep[0], p1 = ep[1], p2 = ep[2], p3 = ep[3];
        u16x8 v0, v1;
        v0[0]=f2bf(p0.x); v0[1]=f2bf(p0.y); v0[2]=f2bf(p0.z); v0[3]=f2bf(p0.w);
        v0[4]=f2bf(p1.x); v0[5]=f2bf(p1.y); v0[6]=f2bf(p1.z); v0[7]=f2bf(p1.w);
        v1[0]=f2bf(p2.x); v1[1]=f2bf(p2.y); v1[2]=f2bf(p2.z); v1[3]=f2bf(p2.w);
        v1[4]=f2bf(p3.x); v1[5]=f2bf(p3.y); v1[6]=f2bf(p3.z); v1[7]=f2bf(p3.w);
        *(u16x8*)(hcat + xr * LDW + xc)     = v0;
        *(u16x8*)(hcat + xr * LDW + xc + 8) = v1;
    }
    __syncthreads();

    const int   mycol = cg * COLS + w * 16 + l15;
    const float bias0 = b0[mycol];
    const float bias1 = b1[mycol];

    const unsigned short* wb0 = wpack + ((size_t)(cg * 256 + w * 32)) * 512 + lane * 8;
    const unsigned short* wb1 = wb0 + (size_t)1024 * 512;   // phase-1 pack half

    const int abase = l15 * LDW + quad * 8;
    const int fl    = bg * NCG;

    for (int t = 0; t < SEQ; ++t) {
        const int par = t & 1;
        const int tgt = t + 1;

        // prefetch x_{t+1} (consumed after B2)
        int tn = (t + 1 < SEQ) ? t + 1 : t;
        int idx = inputs[(rbase + xr) * SEQ + tn];
        const float4* ep = (const float4*)(emb + (size_t)idx * EMB + xc);
        float4 p0 = ep[0], p1 = ep[1], p2 = ep[2], p3 = ep[3];

        // ---- phase 1: pre0 = [x|h0] @ [W0x;W0h] + b0 ----
        f32x4 acc = {bias0, bias0, bias0, bias0};
        RUN_PHASE(acc, 0, wb0);
        {
            unsigned short* dst = h0buf +
                ((size_t)par * BATCH + rbase + quad * 4) * UNITS + mycol;
#pragma unroll
            for (int i = 0; i < 4; ++i)
                __hip_atomic_store(dst + (size_t)i * UNITS,
                                   f2bf(tanh_fast(acc[i])),
                                   __ATOMIC_RELAXED, __HIP_MEMORY_SCOPE_AGENT);
        }
        __syncthreads();                                                  // B1
        if (tid == 0)
            __hip_atomic_store(&flag0[fl + cg], tgt,
                               __ATOMIC_RELEASE, __HIP_MEMORY_SCOPE_AGENT);
        if (tid < NCG)
            while (__hip_atomic_load(&flag0[fl + tid],
                                     __ATOMIC_RELAXED, __HIP_MEMORY_SCOPE_AGENT) < tgt)
                __builtin_amdgcn_s_sleep(1);
        __asm__ volatile("" ::: "memory");
        __syncthreads();                                                  // B2
        {
            // gather full h0' [16x512] -> LDS cols 512..1023 (agent-scope, L2-bypass)
            const unsigned long long* src = (const unsigned long long*)
                (h0buf + ((size_t)par * BATCH + rbase) * UNITS);
            int base = (xr * 512 + xc) >> 2;
            unsigned long long q0 = __hip_atomic_load(src + base + 0, __ATOMIC_RELAXED, __HIP_MEMORY_SCOPE_AGENT);
            unsigned long long q1 = __hip_atomic_load(src + base + 1, __ATOMIC_RELAXED, __HIP_MEMORY_SCOPE_AGENT);
            unsigned long long q2 = __hip_atomic_load(src + base + 2, __ATOMIC_RELAXED, __HIP_MEMORY_SCOPE_AGENT);
            unsigned long long q3 = __hip_atomic_load(src + base + 3, __ATOMIC_RELAXED, __HIP_MEMORY_SCOPE_AGENT);
            unsigned long long* d = (unsigned long long*)&hcat[xr * LDW + 512 + xc];
            d[0] = q0; d[1] = q1; d[2] = q2; d[3] = q3;

            // x_{t+1} -> cols 0..511
            u16x8 v0, v1;
            v0[0]=f2bf(p0.x); v0[1]=f2bf(p0.y); v0[2]=f2bf(p0.z); v0[3]=f2bf(p0.w);
            v0[4]=f2bf(p1.x); v0[5]=f2bf(p1.y); v0[6]=f2bf(p1.z); v0[7]=f2bf(p1.w);
            v1[0]=f2bf(p2.x); v1[1]=f2bf(p2.y); v1[2]=f2bf(p2.z); v1[3]=f2bf(p2.w);
            v1[4]=f2bf(p3.x); v1[5]=f2bf(p3.y); v1[6]=f2bf(p3.z); v1[7]=f2bf(p3.w);
            *(u16x8*)(hcat + xr * LDW + xc)     = v0;
            *(u16x8*)(hcat + xr * LDW + xc + 8) = v1;
        }
        __syncthreads();                                                  // B3

        // ---- phase 2: pre1 = [h0'|h1] @ [W1x;W1h] + b1 ----
        f32x4 acc2 = {bias1, bias1, bias1, bias1};
        RUN_PHASE(acc2, 512, wb1);
        {
            unsigned short* dst = h1buf +
                ((size_t)par * BATCH + rbase + quad * 4) * UNITS + mycol;
#pragma unroll
            for (int i = 0; i < 4; ++i)
                __hip_atomic_store(dst + (size_t)i * UNITS,
                                   f2bf(tanh_fast(acc2[i])),
                                   __ATOMIC_RELAXED, __HIP_MEMORY_SCOPE_AGENT);
        }
        __syncthreads();                                                  // B4
        if (tid == 0)
            __hip_atomic_store(&flag1[fl + cg], tgt,
                               __ATOMIC_RELEASE, __HIP_MEMORY_SCOPE_AGENT);
        if (tid < NCG)
            while (__hip_atomic_load(&flag1[fl + tid],
                                     __ATOMIC_RELAXED, __HIP_MEMORY_SCOPE_AGENT) < tgt)
                __builtin_amdgcn_s_sleep(1);
        __asm__ volatile("" ::: "memory");
        __syncthreads();                                                  // B5
        {
            // gather full h1' -> LDS cols 1024..1535
            const unsigned long long* src = (const unsigned long long*)
                (h1buf + ((size_t)par * BATCH + rbase) * UNITS);
            int base = (xr * 512 + xc) >> 2;
            unsigned long long q0 = __hip_atomic_load(src + base + 0, __ATOMIC_RELAXED, __HIP_MEMORY_SCOPE_AGENT);
            unsigned long long q1 = __hip_atomic_load(src + base + 1, __ATOMIC_RELAXED, __HIP_MEMORY_SCOPE_AGENT);
            unsigned long long q2 = __hip_atomic_load(src + base + 2, __ATOMIC_RELAXED, __HIP_MEMORY_SCOPE_AGENT);
            unsigned long long q3 = __hip_atomic_load(src + base + 3, __ATOMIC_RELAXED, __HIP_MEMORY_SCOPE_AGENT);
            unsigned long long* d = (unsigned long long*)&hcat[xr * LDW + 1024 + xc];
            d[0] = q0; d[1] = q1; d[2] = q2; d[3] = q3;
        }
        // no trailing barrier: next-step B1/B2/B3 order these writes
        // ahead of the next phase-2 reads; phase 1 never touches cols 1024+.
    }
    __syncthreads();

    // ---- epilogue: out = sigmoid(h1 @ Wout + bout); cg 0 blocks only ----
    if (cg == 0) {
#pragma unroll
        for (int rr = 0; rr < 2; ++rr) {
            int r = w * 2 + rr;
            float s = 0.f;
#pragma unroll
            for (int j = 0; j < 8; ++j) {
                int c = lane + 64 * j;
                s += bf2f(hcat[r * LDW + 1024 + c]) * Wout[c];
            }
#pragma unroll
            for (int off = 32; off > 0; off >>= 1) s += __shfl_down(s, off);
            if (lane == 0) {
                float z = s + bout[0];
                out[rbase + r] = 1.f / (1.f + __expf(-z));
            }
        }
    }
}

extern "C" void kernel_launch(void* const* d_in, const int* in_sizes, int n_in,
                              void* d_out, int out_size, void* d_ws, size_t ws_size,
                              hipStream_t stream) {
    const int*   inputs = (const int*)d_in[0];
    const float* emb    = (const float*)d_in[1];
    const float* W0x    = (const float*)d_in[2];
    const float* W0h    = (const float*)d_in[3];
    const float* b0     = (const float*)d_in[4];
    const float* W1x    = (const float*)d_in[5];
    const float* W1h    = (const float*)d_in[6];
    const float* b1     = (const float*)d_in[7];
    const float* Wout   = (const float*)d_in[8];
    const float* bout   = (const float*)d_in[9];
    float*       out    = (float*)d_out;

    unsigned short* wpack = (unsigned short*)d_ws;                      // 2 MB
    unsigned short* h0buf = (unsigned short*)((char*)d_ws + H0_OFF);    // 2 MB
    unsigned short* h1buf = (unsigned short*)((char*)d_ws + H1_OFF);    // 2 MB
    int* flag0 = (int*)((char*)d_ws + FLAG_OFF);                        // 1 KB
    int* flag1 = flag0 + 256;                                           // 1 KB

    hipMemsetAsync((char*)d_ws + FLAG_OFF, 0, 2048, stream);
    pack_weights<<<512, 256, 0, stream>>>(W0x, W0h, W1x, W1h, wpack);
    rnn_ex_kernel<<<NBG * NCG, THREADS, 0, stream>>>(
        inputs, emb, b0, b1, wpack, h0buf, h1buf, flag0, flag1,
        Wout, bout, out);
}